// Round 9
// baseline (583.471 us; speedup 1.0000x reference)
//
#include <hip/hip_runtime.h>
#include <hip/hip_fp16.h>

#define NN 100000
#define NE 1000000
#define HID 64
#define BN_EPS 1e-5f

// scan geometry: 4 elems/thread, 256 threads/block -> 1024 elems/block
#define SCAN_EPB 1024
#define SCAN_NB ((NN + SCAN_EPB - 1) / SCAN_EPB)  // 98
#define DBINS 64

typedef _Float16 hv2 __attribute__((ext_vector_type(2)));
typedef _Float16 hv8 __attribute__((ext_vector_type(8)));

static __device__ __forceinline__ float dot2acc(hv2 a, hv2 b, float c) {
#if __has_builtin(__builtin_amdgcn_fdot2)
    return __builtin_amdgcn_fdot2(a, b, c, false);
#else
    float r = c;
    asm("v_dot2_f32_f16 %0, %1, %2, %0" : "+v"(r) : "v"(a), "v"(b));
    return r;
#endif
}

// ---------------- CSR build (once, reused by all 3 layers) ----------------

// Histogram AND per-edge rank in one pass: rank[e] = #prior edges with same col.
__global__ void hist_rank_kernel(const int* __restrict__ col, int* __restrict__ deg,
                                 unsigned short* __restrict__ rank) {
    int e = blockIdx.x * 256 + threadIdx.x;
    if (e < NE) rank[e] = (unsigned short)atomicAdd(&deg[col[e]], 1);
}

__global__ __launch_bounds__(256) void scan_part(const int* __restrict__ deg,
                                                 int* __restrict__ partials) {
    __shared__ int sh[256];
    int t = threadIdx.x;
    int base = blockIdx.x * SCAN_EPB + t * 4;
    int s = 0;
    if (base + 3 < NN) {
        int4 v = *(const int4*)(deg + base);
        s = v.x + v.y + v.z + v.w;
    } else {
#pragma unroll
        for (int i = 0; i < 4; ++i) if (base + i < NN) s += deg[base + i];
    }
    sh[t] = s;
    __syncthreads();
    for (int d = 128; d > 0; d >>= 1) {
        if (t < d) sh[t] += sh[t + d];
        __syncthreads();
    }
    if (t == 0) partials[blockIdx.x] = sh[0];
}

// Merged: per-block scan of the 98 partials (no scan_mid launch) + local rescan ->
// off, dinv, and a global degree-bin histogram (LDS-aggregated).
__global__ __launch_bounds__(256) void scan_fin(const int* __restrict__ deg,
                                                const int* __restrict__ partials,
                                                int* __restrict__ off,
                                                float* __restrict__ dinv,
                                                int* __restrict__ dbins) {
    __shared__ int pv[128], ps[128], sh[256], hb[DBINS];
    int t = threadIdx.x;
    if (t < DBINS) hb[t] = 0;
    if (t < 128) { int v = (t < SCAN_NB) ? partials[t] : 0; pv[t] = v; ps[t] = v; }
    __syncthreads();
    for (int d = 1; d < 128; d <<= 1) {
        int u = (t >= d && t < 128) ? ps[t - d] : 0;
        __syncthreads();
        if (t < 128) ps[t] += u;
        __syncthreads();
    }
    const int poffb = ps[blockIdx.x] - pv[blockIdx.x];  // exclusive prefix of this block

    int base = blockIdx.x * SCAN_EPB + t * 4;
    int v0 = 0, v1 = 0, v2 = 0, v3 = 0;
    if (base + 3 < NN) {
        int4 v = *(const int4*)(deg + base);
        v0 = v.x; v1 = v.y; v2 = v.z; v3 = v.w;
    } else {
        if (base + 0 < NN) v0 = deg[base + 0];
        if (base + 1 < NN) v1 = deg[base + 1];
        if (base + 2 < NN) v2 = deg[base + 2];
        if (base + 3 < NN) v3 = deg[base + 3];
    }
    int s = v0 + v1 + v2 + v3;
    sh[t] = s;
    __syncthreads();
    for (int d = 1; d < 256; d <<= 1) {
        int u = (t >= d) ? sh[t - d] : 0;
        __syncthreads();
        sh[t] += u;
        __syncthreads();
    }
    int run = poffb + sh[t] - s;
    if (base + 0 < NN) { off[base + 0] = run; run += v0; dinv[base + 0] = rsqrtf((float)(v0 + 1)); atomicAdd(&hb[min(v0, DBINS - 1)], 1); }
    if (base + 1 < NN) { off[base + 1] = run; run += v1; dinv[base + 1] = rsqrtf((float)(v1 + 1)); atomicAdd(&hb[min(v1, DBINS - 1)], 1); }
    if (base + 2 < NN) { off[base + 2] = run; run += v2; dinv[base + 2] = rsqrtf((float)(v2 + 1)); atomicAdd(&hb[min(v2, DBINS - 1)], 1); }
    if (base + 3 < NN) { off[base + 3] = run; run += v3; dinv[base + 3] = rsqrtf((float)(v3 + 1)); atomicAdd(&hb[min(v3, DBINS - 1)], 1); }
    if (blockIdx.x == 0 && t == 0) off[NN] = NE;
    __syncthreads();
    if (t < DBINS && hb[t]) atomicAdd(&dbins[t], hb[t]);
}

// Degree-bucketed node permutation: perm groups nodes of equal (clamped) degree so
// the 8 nodes sharing a wave have near-identical edge counts (kills max-vs-mean loss).
__global__ __launch_bounds__(256) void bucket_fill(const int* __restrict__ deg,
                                                   const int* __restrict__ dbins,
                                                   int* __restrict__ dcur,
                                                   int* __restrict__ perm) {
    __shared__ int dof[DBINS];
    int t = threadIdx.x;
    if (t < DBINS) {  // in-wave exclusive scan of the 64 bins (lanes 0..63 of wave 0)
        int v = dbins[t];
        int x = v;
#pragma unroll
        for (int d = 1; d < DBINS; d <<= 1) {
            int u = __shfl_up(x, d);
            if ((t & 63) >= d) x += u;
        }
        dof[t] = x - v;
    }
    __syncthreads();
    int n = blockIdx.x * 256 + t;
    if (n < NN) {
        int k = min(deg[n], DBINS - 1);
        int pos = dof[k] + atomicAdd(&dcur[k], 1);
        perm[pos] = n;
    }
}

// Atomic-free, weight-free fill: csr[off[col]+rank] = src. (4B/edge)
__global__ void fill_kernel(const int* __restrict__ row, const int* __restrict__ col,
                            const unsigned short* __restrict__ rank,
                            const int* __restrict__ off, int* __restrict__ csr) {
    int e = blockIdx.x * 256 + threadIdx.x;
    if (e >= NE) return;
    csr[off[col[e]] + (int)rank[e]] = row[e];
}

// Scale + pad + fp16-ify x0: xp[n][k] = half(dinv[n]*x0[n][k]) for k<37, 0 for k in [37,40)
__global__ void pad_kernel(const float* __restrict__ x, const float* __restrict__ dinv,
                           _Float16* __restrict__ xp) {
    int i = blockIdx.x * 256 + threadIdx.x;
    if (i >= NN * 40) return;
    int n = i / 40, k = i - n * 40;
    float v = (k < 37) ? dinv[n] * x[n * 37 + k] : 0.f;
    xp[i] = (_Float16)v;
}

// ---------------- Fused layer ----------------
// Geometry: block = 4 waves; wave owns 8 nodes taken from perm[] (degree-equalized).
//   lane = (slot in [0,8)) * 8 + (c in [0,8));  slot's node = perm[wave_base + slot].
// Gather: 8-lane group accumulates its node's full fp16 row (pk_add), 4-deep unroll.
// GEMM: thread = output col l; W column preloaded in NC*4 half2 VGPRs; v_dot2_f32_f16;
//       LDS row reads are wave-uniform ds_read_b128 (broadcast, conflict-free).
template <int NC, int KREAL, bool RES, bool W16, bool W32>
__global__ __launch_bounds__(256) void layer_kernel(
    const _Float16* __restrict__ xin, const float* __restrict__ dinv,
    const int* __restrict__ off, const int* __restrict__ csr,
    const int* __restrict__ perm,
    const float* __restrict__ W, const float* __restrict__ b,
    const float* __restrict__ gamma, const float* __restrict__ beta,
    const float* __restrict__ mean, const float* __restrict__ var,
    _Float16* __restrict__ out16, float* __restrict__ out32) {
    __shared__ _Float16 xs[4][8][NC * 8];
    const int tid  = threadIdx.x;
    const int w    = tid >> 6;
    const int l    = tid & 63;
    const int slot = l >> 3;
    const int c    = l & 7;
    const int nbase = (blockIdx.x * 4 + w) * 8;   // 3125*4*8 == 100000 exactly
    const hv8* __restrict__ x8 = (const hv8*)xin;

    // ---- W column preload: wc[q] packs rows (2q, 2q+1) of column l ----
    hv2 wc[NC * 4];
#pragma unroll
    for (int q = 0; q < NC * 4; ++q) {
        float w0 = (2 * q     < KREAL) ? W[(2 * q)     * HID + l] : 0.f;
        float w1 = (2 * q + 1 < KREAL) ? W[(2 * q + 1) * HID + l] : 0.f;
        hv2 t = {(_Float16)w0, (_Float16)w1};
        wc[q] = t;
    }

    // ---- gather phase (8-lane group per node, fp16 packed accumulate) ----
    const int n = perm[nbase + slot];
    if (c < NC) {
        hv8 accA = x8[(size_t)n * NC + c];   // self loop (prescaled row)
        hv8 accB = (hv8)(_Float16)0.f;
        int p  = off[n];                     // slot-uniform
        int p1 = off[n + 1];
        for (; p + 3 < p1; p += 4) {         // 4 gathers in flight per lane
            int s0 = csr[p], s1 = csr[p + 1], s2 = csr[p + 2], s3 = csr[p + 3];
            hv8 v0 = x8[(size_t)s0 * NC + c];
            hv8 v1 = x8[(size_t)s1 * NC + c];
            hv8 v2 = x8[(size_t)s2 * NC + c];
            hv8 v3 = x8[(size_t)s3 * NC + c];
            accA += v0; accB += v1; accA += v2; accB += v3;
        }
        if (p + 1 < p1) {
            hv8 v0 = x8[(size_t)csr[p] * NC + c];
            hv8 v1 = x8[(size_t)csr[p + 1] * NC + c];
            accA += v0; accB += v1;
            p += 2;
        }
        if (p < p1) accA += x8[(size_t)csr[p] * NC + c];
        *(hv8*)&xs[w][slot][c * 8] = accA + accB;
    }
    __syncthreads();

    // ---- GEMM + epilogue: thread = col l, loop over the wave's 8 nodes ----
    const float aa = gamma[l] * rsqrtf(var[l] + BN_EPS);
    const float cc = fmaf(b[l] - mean[l], aa, beta[l]);
    for (int i = 0; i < 8; ++i) {
        const int ni = perm[nbase + i];      // wave-uniform
        float s = 0.f;
#pragma unroll
        for (int q0 = 0; q0 < NC; ++q0) {
            union { hv8 v; hv2 h[4]; } u;
            u.v = *(const hv8*)&xs[w][i][q0 * 8];   // wave-uniform b128 broadcast
            s = dot2acc(u.h[0], wc[q0 * 4 + 0], s);
            s = dot2acc(u.h[1], wc[q0 * 4 + 1], s);
            s = dot2acc(u.h[2], wc[q0 * 4 + 2], s);
            s = dot2acc(u.h[3], wc[q0 * 4 + 3], s);
        }
        const float di = dinv[ni];
        float v = fmaf(s, di * aa, cc);
        v = fmaxf(v, 0.f);
        const size_t idx = (size_t)ni * HID + l;
        if (RES) v = fmaf((float)xin[(size_t)ni * (NC * 8) + l], 1.f / di, v);
        if (W32) out32[idx] = v;
        if (W16) out16[idx] = (_Float16)(v * di);
    }
}

// ---------------- Launch ----------------

static inline size_t align256(size_t x) { return (x + 255) & ~(size_t)255; }

extern "C" void kernel_launch(void* const* d_in, const int* in_sizes, int n_in,
                              void* d_out, int out_size, void* d_ws, size_t ws_size,
                              hipStream_t stream) {
    const float* x0   = (const float*)d_in[0];
    const int*   ei   = (const int*)d_in[1];
    const float* W1   = (const float*)d_in[2];
    const float* W2   = (const float*)d_in[3];
    const float* W3   = (const float*)d_in[4];
    const float* bb   = (const float*)d_in[5];
    const float* gam  = (const float*)d_in[6];
    const float* bet  = (const float*)d_in[7];
    const float* rmn  = (const float*)d_in[8];
    const float* rvr  = (const float*)d_in[9];
    float* out = (float*)d_out;

    char* w = (char*)d_ws;
    // deg, dbins, dcur contiguous -> single memset
    int*      deg      = (int*)w;      w += align256((size_t)(NN + 2 * DBINS) * 4);
    int*      dbins    = deg + NN;
    int*      dcur     = deg + NN + DBINS;
    int*      off      = (int*)w;      w += align256((size_t)(NN + 1) * 4);
    float*    dinv     = (float*)w;    w += align256((size_t)NN * 4);
    unsigned short* rank = (unsigned short*)w; w += align256((size_t)NE * 2);
    int*      partials = (int*)w;      w += align256((size_t)SCAN_NB * 4);
    int*      csr      = (int*)w;      w += align256((size_t)NE * 4);
    int*      perm     = (int*)w;      w += align256((size_t)NN * 4);
    _Float16* xpad     = (_Float16*)w; w += align256((size_t)NN * 40 * 2);
    _Float16* hA16     = (_Float16*)w; w += align256((size_t)NN * HID * 2);
    _Float16* hB16     = (_Float16*)w; w += align256((size_t)NN * HID * 2);

    const int* row = ei;
    const int* col = ei + NE;

    dim3 blk(256);
    dim3 grE((NE + 255) / 256);
    dim3 grN((NN + 255) / 256);
    dim3 grL(NN / 32);  // 3125 blocks * 32 nodes == 100000 exactly
    dim3 grPad((NN * 40 + 255) / 256);

    // CSR build + degree-bucket permutation
    hipMemsetAsync(deg, 0, (size_t)(NN + 2 * DBINS) * 4, stream);
    hist_rank_kernel<<<grE, blk, 0, stream>>>(col, deg, rank);
    scan_part<<<SCAN_NB, 256, 0, stream>>>(deg, partials);
    scan_fin<<<SCAN_NB, 256, 0, stream>>>(deg, partials, off, dinv, dbins);
    bucket_fill<<<grN, blk, 0, stream>>>(deg, dbins, dcur, perm);
    fill_kernel<<<grE, blk, 0, stream>>>(row, col, rank, off, csr);
    pad_kernel<<<grPad, blk, 0, stream>>>(x0, dinv, xpad);

    // Layer 0: K=37 (rows padded to 40 halfs, NC=5), no residual -> hA16
    layer_kernel<5, 37, false, true, false><<<grL, blk, 0, stream>>>(
        xpad, dinv, off, csr, perm, W1, bb + 0, gam + 0, bet + 0, rmn + 0, rvr + 0,
        hA16, nullptr);
    // Layer 1: K=64 (NC=8), residual (recovered from hA16) -> hB16
    layer_kernel<8, 64, true, true, false><<<grL, blk, 0, stream>>>(
        hA16, dinv, off, csr, perm, W2, bb + 64, gam + 64, bet + 64, rmn + 64, rvr + 64,
        hB16, nullptr);
    // Layer 2: K=64 (NC=8), residual (recovered from hB16) -> d_out (fp32)
    layer_kernel<8, 64, true, false, true><<<grL, blk, 0, stream>>>(
        hB16, dinv, off, csr, perm, W3, bb + 128, gam + 128, bet + 128, rmn + 128, rvr + 128,
        nullptr, out);
}

// Round 10
// 258.661 us; speedup vs baseline: 2.2557x; 2.2557x over previous
//
#include <hip/hip_runtime.h>
#include <hip/hip_fp16.h>

#define NN 100000
#define NE 1000000
#define HID 64
#define BN_EPS 1e-5f

// scan geometry: 4 elems/thread, 256 threads/block -> 1024 elems/block
#define SCAN_EPB 1024
#define SCAN_NB ((NN + SCAN_EPB - 1) / SCAN_EPB)  // 98
#define DBINS 64

typedef _Float16 hv2 __attribute__((ext_vector_type(2)));
typedef _Float16 hv8 __attribute__((ext_vector_type(8)));

static __device__ __forceinline__ float dot2acc(hv2 a, hv2 b, float c) {
#if __has_builtin(__builtin_amdgcn_fdot2)
    return __builtin_amdgcn_fdot2(a, b, c, false);
#else
    float r = c;
    asm("v_dot2_f32_f16 %0, %1, %2, %0" : "+v"(r) : "v"(a), "v"(b));
    return r;
#endif
}

// ---------------- CSR build (once, reused by all 3 layers) ----------------

// Histogram AND per-edge rank in one pass: rank[e] = #prior edges with same col.
__global__ void hist_rank_kernel(const int* __restrict__ col, int* __restrict__ deg,
                                 unsigned short* __restrict__ rank) {
    int e = blockIdx.x * 256 + threadIdx.x;
    if (e < NE) rank[e] = (unsigned short)atomicAdd(&deg[col[e]], 1);
}

__global__ __launch_bounds__(256) void scan_part(const int* __restrict__ deg,
                                                 int* __restrict__ partials) {
    __shared__ int sh[256];
    int t = threadIdx.x;
    int base = blockIdx.x * SCAN_EPB + t * 4;
    int s = 0;
    if (base + 3 < NN) {
        int4 v = *(const int4*)(deg + base);
        s = v.x + v.y + v.z + v.w;
    } else {
#pragma unroll
        for (int i = 0; i < 4; ++i) if (base + i < NN) s += deg[base + i];
    }
    sh[t] = s;
    __syncthreads();
    for (int d = 128; d > 0; d >>= 1) {
        if (t < d) sh[t] += sh[t + d];
        __syncthreads();
    }
    if (t == 0) partials[blockIdx.x] = sh[0];
}

// Merged: per-block scan of the 98 partials (no scan_mid launch) + local rescan ->
// off, dinv, and a global degree-bin histogram (LDS-aggregated).
__global__ __launch_bounds__(256) void scan_fin(const int* __restrict__ deg,
                                                const int* __restrict__ partials,
                                                int* __restrict__ off,
                                                float* __restrict__ dinv,
                                                int* __restrict__ dbins) {
    __shared__ int pv[128], ps[128], sh[256], hb[DBINS];
    int t = threadIdx.x;
    if (t < DBINS) hb[t] = 0;
    if (t < 128) { int v = (t < SCAN_NB) ? partials[t] : 0; pv[t] = v; ps[t] = v; }
    __syncthreads();
    for (int d = 1; d < 128; d <<= 1) {
        int u = (t >= d && t < 128) ? ps[t - d] : 0;
        __syncthreads();
        if (t < 128) ps[t] += u;
        __syncthreads();
    }
    const int poffb = ps[blockIdx.x] - pv[blockIdx.x];  // exclusive prefix of this block

    int base = blockIdx.x * SCAN_EPB + t * 4;
    int v0 = 0, v1 = 0, v2 = 0, v3 = 0;
    if (base + 3 < NN) {
        int4 v = *(const int4*)(deg + base);
        v0 = v.x; v1 = v.y; v2 = v.z; v3 = v.w;
    } else {
        if (base + 0 < NN) v0 = deg[base + 0];
        if (base + 1 < NN) v1 = deg[base + 1];
        if (base + 2 < NN) v2 = deg[base + 2];
        if (base + 3 < NN) v3 = deg[base + 3];
    }
    int s = v0 + v1 + v2 + v3;
    sh[t] = s;
    __syncthreads();
    for (int d = 1; d < 256; d <<= 1) {
        int u = (t >= d) ? sh[t - d] : 0;
        __syncthreads();
        sh[t] += u;
        __syncthreads();
    }
    int run = poffb + sh[t] - s;
    if (base + 0 < NN) { off[base + 0] = run; run += v0; dinv[base + 0] = rsqrtf((float)(v0 + 1)); atomicAdd(&hb[min(v0, DBINS - 1)], 1); }
    if (base + 1 < NN) { off[base + 1] = run; run += v1; dinv[base + 1] = rsqrtf((float)(v1 + 1)); atomicAdd(&hb[min(v1, DBINS - 1)], 1); }
    if (base + 2 < NN) { off[base + 2] = run; run += v2; dinv[base + 2] = rsqrtf((float)(v2 + 1)); atomicAdd(&hb[min(v2, DBINS - 1)], 1); }
    if (base + 3 < NN) { off[base + 3] = run; run += v3; dinv[base + 3] = rsqrtf((float)(v3 + 1)); atomicAdd(&hb[min(v3, DBINS - 1)], 1); }
    if (blockIdx.x == 0 && t == 0) off[NN] = NE;
    __syncthreads();
    if (t < DBINS && hb[t]) atomicAdd(&dbins[t], hb[t]);
}

// Degree-bucketed node permutation, contention-free:
// per-block LDS histogram -> ONE global atomic per (block,bin) -> in-block rank scatter.
__global__ __launch_bounds__(256) void bucket_fill(const int* __restrict__ deg,
                                                   const int* __restrict__ dbins,
                                                   int* __restrict__ dcur,
                                                   int* __restrict__ perm) {
    __shared__ int dof[DBINS], cnt[DBINS], bbase[DBINS], cur2[DBINS];
    int t = threadIdx.x;
    if (t < DBINS) {  // in-wave exclusive scan of the 64 global bins (wave 0)
        int v = dbins[t];
        int x = v;
#pragma unroll
        for (int d = 1; d < DBINS; d <<= 1) {
            int u = __shfl_up(x, d);
            if ((t & 63) >= d) x += u;
        }
        dof[t] = x - v;
        cnt[t] = 0;
        cur2[t] = 0;
    }
    __syncthreads();
    int n = blockIdx.x * 256 + t;
    int k = -1;
    if (n < NN) {
        k = min(deg[n], DBINS - 1);
        atomicAdd(&cnt[k], 1);               // LDS atomic
    }
    __syncthreads();
    if (t < DBINS && cnt[t] > 0) bbase[t] = atomicAdd(&dcur[t], cnt[t]);  // 1 global atomic/bin
    __syncthreads();
    if (n < NN) {
        int r = atomicAdd(&cur2[k], 1);      // LDS atomic: in-block rank
        perm[dof[k] + bbase[k] + r] = n;
    }
}

// Atomic-free, weight-free fill: csr[off[col]+rank] = src. (4B/edge)
__global__ void fill_kernel(const int* __restrict__ row, const int* __restrict__ col,
                            const unsigned short* __restrict__ rank,
                            const int* __restrict__ off, int* __restrict__ csr) {
    int e = blockIdx.x * 256 + threadIdx.x;
    if (e >= NE) return;
    csr[off[col[e]] + (int)rank[e]] = row[e];
}

// Scale + pad + fp16-ify x0: xp[n][k] = half(dinv[n]*x0[n][k]) for k<37, 0 for k in [37,40)
__global__ void pad_kernel(const float* __restrict__ x, const float* __restrict__ dinv,
                           _Float16* __restrict__ xp) {
    int i = blockIdx.x * 256 + threadIdx.x;
    if (i >= NN * 40) return;
    int n = i / 40, k = i - n * 40;
    float v = (k < 37) ? dinv[n] * x[n * 37 + k] : 0.f;
    xp[i] = (_Float16)v;
}

// ---------------- Fused layer ----------------
// Geometry: block = 4 waves; wave owns 8 nodes taken from perm[] (degree-equalized).
//   lane = (slot in [0,8)) * 8 + (c in [0,8));  slot's node = perm[wave_base + slot].
// Gather: 8-lane group accumulates its node's full fp16 row (pk_add), 4-deep unroll.
// GEMM: thread = output col l; W column preloaded in NC*4 half2 VGPRs; v_dot2_f32_f16;
//       LDS row reads are wave-uniform ds_read_b128 (broadcast, conflict-free).
template <int NC, int KREAL, bool RES, bool W16, bool W32>
__global__ __launch_bounds__(256) void layer_kernel(
    const _Float16* __restrict__ xin, const float* __restrict__ dinv,
    const int* __restrict__ off, const int* __restrict__ csr,
    const int* __restrict__ perm,
    const float* __restrict__ W, const float* __restrict__ b,
    const float* __restrict__ gamma, const float* __restrict__ beta,
    const float* __restrict__ mean, const float* __restrict__ var,
    _Float16* __restrict__ out16, float* __restrict__ out32) {
    __shared__ _Float16 xs[4][8][NC * 8];
    const int tid  = threadIdx.x;
    const int w    = tid >> 6;
    const int l    = tid & 63;
    const int slot = l >> 3;
    const int c    = l & 7;
    const int nbase = (blockIdx.x * 4 + w) * 8;   // 3125*4*8 == 100000 exactly
    const hv8* __restrict__ x8 = (const hv8*)xin;

    // ---- W column preload: wc[q] packs rows (2q, 2q+1) of column l ----
    hv2 wc[NC * 4];
#pragma unroll
    for (int q = 0; q < NC * 4; ++q) {
        float w0 = (2 * q     < KREAL) ? W[(2 * q)     * HID + l] : 0.f;
        float w1 = (2 * q + 1 < KREAL) ? W[(2 * q + 1) * HID + l] : 0.f;
        hv2 t = {(_Float16)w0, (_Float16)w1};
        wc[q] = t;
    }

    // ---- gather phase (8-lane group per node, fp16 packed accumulate) ----
    const int n = perm[nbase + slot];
    if (c < NC) {
        hv8 accA = x8[(size_t)n * NC + c];   // self loop (prescaled row)
        hv8 accB = (hv8)(_Float16)0.f;
        int p  = off[n];                     // slot-uniform
        int p1 = off[n + 1];
        for (; p + 3 < p1; p += 4) {         // 4 gathers in flight per lane
            int s0 = csr[p], s1 = csr[p + 1], s2 = csr[p + 2], s3 = csr[p + 3];
            hv8 v0 = x8[(size_t)s0 * NC + c];
            hv8 v1 = x8[(size_t)s1 * NC + c];
            hv8 v2 = x8[(size_t)s2 * NC + c];
            hv8 v3 = x8[(size_t)s3 * NC + c];
            accA += v0; accB += v1; accA += v2; accB += v3;
        }
        if (p + 1 < p1) {
            hv8 v0 = x8[(size_t)csr[p] * NC + c];
            hv8 v1 = x8[(size_t)csr[p + 1] * NC + c];
            accA += v0; accB += v1;
            p += 2;
        }
        if (p < p1) accA += x8[(size_t)csr[p] * NC + c];
        *(hv8*)&xs[w][slot][c * 8] = accA + accB;
    }
    __syncthreads();

    // ---- GEMM + epilogue: thread = col l, loop over the wave's 8 nodes ----
    const float aa = gamma[l] * rsqrtf(var[l] + BN_EPS);
    const float cc = fmaf(b[l] - mean[l], aa, beta[l]);
    for (int i = 0; i < 8; ++i) {
        const int ni = perm[nbase + i];      // wave-uniform
        float s = 0.f;
#pragma unroll
        for (int q0 = 0; q0 < NC; ++q0) {
            union { hv8 v; hv2 h[4]; } u;
            u.v = *(const hv8*)&xs[w][i][q0 * 8];   // wave-uniform b128 broadcast
            s = dot2acc(u.h[0], wc[q0 * 4 + 0], s);
            s = dot2acc(u.h[1], wc[q0 * 4 + 1], s);
            s = dot2acc(u.h[2], wc[q0 * 4 + 2], s);
            s = dot2acc(u.h[3], wc[q0 * 4 + 3], s);
        }
        const float di = dinv[ni];
        float v = fmaf(s, di * aa, cc);
        v = fmaxf(v, 0.f);
        const size_t idx = (size_t)ni * HID + l;
        if (RES) v = fmaf((float)xin[(size_t)ni * (NC * 8) + l], 1.f / di, v);
        if (W32) out32[idx] = v;
        if (W16) out16[idx] = (_Float16)(v * di);
    }
}

// ---------------- Launch ----------------

static inline size_t align256(size_t x) { return (x + 255) & ~(size_t)255; }

extern "C" void kernel_launch(void* const* d_in, const int* in_sizes, int n_in,
                              void* d_out, int out_size, void* d_ws, size_t ws_size,
                              hipStream_t stream) {
    const float* x0   = (const float*)d_in[0];
    const int*   ei   = (const int*)d_in[1];
    const float* W1   = (const float*)d_in[2];
    const float* W2   = (const float*)d_in[3];
    const float* W3   = (const float*)d_in[4];
    const float* bb   = (const float*)d_in[5];
    const float* gam  = (const float*)d_in[6];
    const float* bet  = (const float*)d_in[7];
    const float* rmn  = (const float*)d_in[8];
    const float* rvr  = (const float*)d_in[9];
    float* out = (float*)d_out;

    char* w = (char*)d_ws;
    // deg, dbins, dcur contiguous -> single memset
    int*      deg      = (int*)w;      w += align256((size_t)(NN + 2 * DBINS) * 4);
    int*      dbins    = deg + NN;
    int*      dcur     = deg + NN + DBINS;
    int*      off      = (int*)w;      w += align256((size_t)(NN + 1) * 4);
    float*    dinv     = (float*)w;    w += align256((size_t)NN * 4);
    unsigned short* rank = (unsigned short*)w; w += align256((size_t)NE * 2);
    int*      partials = (int*)w;      w += align256((size_t)SCAN_NB * 4);
    int*      csr      = (int*)w;      w += align256((size_t)NE * 4);
    int*      perm     = (int*)w;      w += align256((size_t)NN * 4);
    _Float16* xpad     = (_Float16*)w; w += align256((size_t)NN * 40 * 2);
    _Float16* hA16     = (_Float16*)w; w += align256((size_t)NN * HID * 2);
    _Float16* hB16     = (_Float16*)w; w += align256((size_t)NN * HID * 2);

    const int* row = ei;
    const int* col = ei + NE;

    dim3 blk(256);
    dim3 grE((NE + 255) / 256);
    dim3 grN((NN + 255) / 256);
    dim3 grL(NN / 32);  // 3125 blocks * 32 nodes == 100000 exactly
    dim3 grPad((NN * 40 + 255) / 256);

    // CSR build + degree-bucket permutation
    hipMemsetAsync(deg, 0, (size_t)(NN + 2 * DBINS) * 4, stream);
    hist_rank_kernel<<<grE, blk, 0, stream>>>(col, deg, rank);
    scan_part<<<SCAN_NB, 256, 0, stream>>>(deg, partials);
    scan_fin<<<SCAN_NB, 256, 0, stream>>>(deg, partials, off, dinv, dbins);
    bucket_fill<<<grN, blk, 0, stream>>>(deg, dbins, dcur, perm);
    fill_kernel<<<grE, blk, 0, stream>>>(row, col, rank, off, csr);
    pad_kernel<<<grPad, blk, 0, stream>>>(x0, dinv, xpad);

    // Layer 0: K=37 (rows padded to 40 halfs, NC=5), no residual -> hA16
    layer_kernel<5, 37, false, true, false><<<grL, blk, 0, stream>>>(
        xpad, dinv, off, csr, perm, W1, bb + 0, gam + 0, bet + 0, rmn + 0, rvr + 0,
        hA16, nullptr);
    // Layer 1: K=64 (NC=8), residual (recovered from hA16) -> hB16
    layer_kernel<8, 64, true, true, false><<<grL, blk, 0, stream>>>(
        hA16, dinv, off, csr, perm, W2, bb + 64, gam + 64, bet + 64, rmn + 64, rvr + 64,
        hB16, nullptr);
    // Layer 2: K=64 (NC=8), residual (recovered from hB16) -> d_out (fp32)
    layer_kernel<8, 64, true, false, true><<<grL, blk, 0, stream>>>(
        hB16, dinv, off, csr, perm, W3, bb + 128, gam + 128, bet + 128, rmn + 128, rvr + 128,
        nullptr, out);
}